// Round 8
// baseline (556.570 us; speedup 1.0000x reference)
//
#include <hip/hip_runtime.h>
#include <cmath>
#include <cstdint>

constexpr int T_STEPS = 512;
constexpr int BATCH   = 1024;
constexpr int DIM     = 128;
constexpr int LATENT  = 256;
constexpr int OUT_DIM = 64;
constexpr int ROWS    = 16;               // batch rows per block
constexpr int NKSUB   = 48;               // (256+128)/8 k-subtiles

typedef __attribute__((ext_vector_type(8))) short bf16x8;   // MFMA A/B frag
typedef __attribute__((ext_vector_type(4))) float f32x4;    // MFMA C/D frag

__device__ __forceinline__ uint32_t f2bf(float f) {
    uint32_t u = __builtin_bit_cast(uint32_t, f);
    return (u + 0x7FFFu + ((u >> 16) & 1u)) >> 16;
}
__device__ __forceinline__ float bf2f(uint32_t b) {
    return __builtin_bit_cast(float, b << 16);
}
__device__ __forceinline__ uint32_t pk2(float a, float b) {
    return f2bf(a) | (f2bf(b) << 16);
}
// tanh(v) = 1 - 2/(e^{2v}+1); native exp2+rcp; saturates correctly at +-inf.
__device__ __forceinline__ float fast_tanh(float v) {
    float e = __builtin_amdgcn_exp2f(v * 2.885390081777927f);   // e^{2v}
    return __builtin_fmaf(-2.0f, __builtin_amdgcn_rcpf(e + 1.0f), 1.0f);
}
__device__ __forceinline__ float fast_sigmoid(float v) {
    float e = __builtin_amdgcn_exp2f(v * -1.4426950408889634f); // e^{-v}
    return __builtin_amdgcn_rcpf(e + 1.0f);
}
// lane 2i <-> 2i+1 value swap, pure-VALU DPP (quad_perm [1,0,3,2] = 0xB1)
__device__ __forceinline__ uint32_t dpp_xor1(uint32_t v) {
    return (uint32_t)__builtin_amdgcn_update_dpp(0, (int)v, 0xB1, 0xF, 0xF, true);
}

// grid = 64 blocks x 16 batch rows; block = 256 threads = 4 waves (1/SIMD).
// Wave wv owns cols [64wv, 64wv+64) = 4 col-tiles: each A-frag ds_read is
// reused for 4 MFMAs -> A-reads 48 b128/step/CU (r7: 96, LDS-issue-bound).
// B = 48 named bf16x8 frags = 192 AGPRs: fits because waves_per_eu(1,1)
// (max=1!) raises the per-wave budget to the full 512-reg pool. r6 used
// waves_per_eu(1) = MIN only -> allocator still targeted 128 and spilled.
// h-writeback: DPP lane-pair col packing -> 8 all-lane ds_write_b32/wave.
__global__ void
__attribute__((amdgpu_flat_work_group_size(256, 256), amdgpu_waves_per_eu(1, 1)))
rnn_mfma_w4t4(const float* __restrict__ x,    // [512][1024][128]
              const float* __restrict__ h0,   // [1024][256]
              const float* __restrict__ Wi,   // [128][256]
              const float* __restrict__ bi,   // [256]
              const float* __restrict__ Wh,   // [256][256]
              const float* __restrict__ Wd,   // [256][64]
              const float* __restrict__ bd,   // [64]
              float* __restrict__ out)        // [1024][64]
{
    __shared__ uint16_t als[2][NKSUB * 128];  // [ksub][row16][8] u16, dbuf

    const int tid   = threadIdx.x;
    const int lane  = tid & 63;
    const int wv    = tid >> 6;              // 0..3
    const int b0    = blockIdx.x * ROWS;
    const int row16 = lane & 15;
    const int kgrp  = lane >> 4;             // 0..3
    const int col0  = (wv << 6) + row16;     // col of tile 0 (tiles: +16 each)

#define LOADB(NAME, P)                                                      \
    bf16x8 NAME; {                                                          \
        const float* _p = (P);                                              \
        NAME[0] = (short)f2bf(_p[0]);                                       \
        NAME[1] = (short)f2bf(_p[1 * LATENT]);                              \
        NAME[2] = (short)f2bf(_p[2 * LATENT]);                              \
        NAME[3] = (short)f2bf(_p[3 * LATENT]);                              \
        NAME[4] = (short)f2bf(_p[4 * LATENT]);                              \
        NAME[5] = (short)f2bf(_p[5 * LATENT]);                              \
        NAME[6] = (short)f2bf(_p[6 * LATENT]);                              \
        NAME[7] = (short)f2bf(_p[7 * LATENT]);                              \
    }
#define BPH(KK, CT) (Wh + (size_t)((KK) * 32 + kgrp * 8) * LATENT + col0 + ((CT) << 4))
#define BPX(KK, CT) (Wi + (size_t)(((KK) - 8) * 32 + kgrp * 8) * LATENT + col0 + ((CT) << 4))
#define DECL4H(KK) LOADB(B##KK##_0, BPH(KK,0)) LOADB(B##KK##_1, BPH(KK,1)) \
                   LOADB(B##KK##_2, BPH(KK,2)) LOADB(B##KK##_3, BPH(KK,3))
#define DECL4X(KK) LOADB(B##KK##_0, BPX(KK,0)) LOADB(B##KK##_1, BPX(KK,1)) \
                   LOADB(B##KK##_2, BPX(KK,2)) LOADB(B##KK##_3, BPX(KK,3))
    DECL4H(0) DECL4H(1) DECL4H(2)  DECL4H(3)
    DECL4H(4) DECL4H(5) DECL4H(6)  DECL4H(7)
    DECL4X(8) DECL4X(9) DECL4X(10) DECL4X(11)

    const float cb0 = bi[col0];
    const float cb1 = bi[col0 + 16];
    const float cb2 = bi[col0 + 32];
    const float cb3 = bi[col0 + 48];

    // ---- prologue: stage h0 and x(t=0) into als[0] (256 threads) ----
    const int pr = tid & 15;                 // batch row
    const int pq = tid >> 4;                 // 0..15
    {
        const float* hrow = h0 + (size_t)(b0 + pr) * LATENT + (pq << 4);
        float4 a0 = reinterpret_cast<const float4*>(hrow)[0];
        float4 a1 = reinterpret_cast<const float4*>(hrow)[1];
        float4 a2 = reinterpret_cast<const float4*>(hrow)[2];
        float4 a3 = reinterpret_cast<const float4*>(hrow)[3];
        *reinterpret_cast<uint4*>(&als[0][((pq * 2) * 16 + pr) * 8]) =
            make_uint4(pk2(a0.x, a0.y), pk2(a0.z, a0.w),
                       pk2(a1.x, a1.y), pk2(a1.z, a1.w));
        *reinterpret_cast<uint4*>(&als[0][((pq * 2 + 1) * 16 + pr) * 8]) =
            make_uint4(pk2(a2.x, a2.y), pk2(a2.z, a2.w),
                       pk2(a3.x, a3.y), pk2(a3.z, a3.w));
        const float* xrow = x + (size_t)(b0 + pr) * DIM + (pq << 3);
        float4 b0v = reinterpret_cast<const float4*>(xrow)[0];
        float4 b1v = reinterpret_cast<const float4*>(xrow)[1];
        *reinterpret_cast<uint4*>(&als[0][((32 + pq) * 16 + pr) * 8]) =
            make_uint4(pk2(b0v.x, b0v.y), pk2(b0v.z, b0v.w),
                       pk2(b1v.x, b1v.y), pk2(b1v.z, b1v.w));
    }
    __syncthreads();

    const int aoff = kgrp * 128 + row16 * 8;     // A-frag base (u16 idx)
    const float* xp = x + ((size_t)BATCH + b0 + pr) * DIM + (pq << 3);  // t=1
    const int xwb = ((32 + pq) * 16 + pr) * 8;

    // writeback bases (constant over t): paired-col b32 writes.
    const int par = lane & 1;                    // pair parity
    const int Rr  = kgrp * 4 + par * 2;          // first row this lane writes
#define WBB(CT) (((((col0 + ((CT) << 4) - par) >> 3) * 128) +               \
                  ((col0 + ((CT) << 4) - par) & 7)) + Rr * 8)
    const int wb0 = WBB(0), wb1 = WBB(1), wb2 = WBB(2), wb3 = WBB(3);

    int cur = 0;
    for (int t = 0; t < T_STEPS; ++t) {
        const bool pf = (t + 1 < T_STEPS);
        float4 xv0, xv1;
        if (pf) {
            xv0 = reinterpret_cast<const float4*>(xp)[0];
            xv1 = reinterpret_cast<const float4*>(xp)[1];
            xp += (size_t)BATCH * DIM;
        }

        f32x4 c0 = {cb0, cb0, cb0, cb0};
        f32x4 c1 = {cb1, cb1, cb1, cb1};
        f32x4 c2 = {cb2, cb2, cb2, cb2};
        f32x4 c3 = {cb3, cb3, cb3, cb3};
        const uint16_t* ab = &als[cur][aoff];
#define MSTEP(KK) {                                                         \
        const bf16x8 a = *reinterpret_cast<const bf16x8*>(ab + (KK) * 512); \
        c0 = __builtin_amdgcn_mfma_f32_16x16x32_bf16(a, B##KK##_0, c0, 0, 0, 0); \
        c1 = __builtin_amdgcn_mfma_f32_16x16x32_bf16(a, B##KK##_1, c1, 0, 0, 0); \
        c2 = __builtin_amdgcn_mfma_f32_16x16x32_bf16(a, B##KK##_2, c2, 0, 0, 0); \
        c3 = __builtin_amdgcn_mfma_f32_16x16x32_bf16(a, B##KK##_3, c3, 0, 0, 0); }
        MSTEP(0) MSTEP(1) MSTEP(2)  MSTEP(3)
        MSTEP(4) MSTEP(5) MSTEP(6)  MSTEP(7)
        MSTEP(8) MSTEP(9) MSTEP(10) MSTEP(11)

        const int nxt = cur ^ 1;
        uint16_t* lsn = als[nxt];
        // h_{t+1} = tanh(c): DPP-pack col pairs -> 2 b32 writes per tile.
        // even lane writes rows R,R+1 of (c,c+1); odd lane rows R+2,R+3.
#define WB(CT, CV, WBASE) {                                                 \
        const uint32_t v0 = f2bf(fast_tanh(CV[0]));                         \
        const uint32_t v1 = f2bf(fast_tanh(CV[1]));                         \
        const uint32_t v2 = f2bf(fast_tanh(CV[2]));                         \
        const uint32_t v3 = f2bf(fast_tanh(CV[3]));                         \
        const uint32_t q0 = dpp_xor1(v0), q1 = dpp_xor1(v1);                \
        const uint32_t q2 = dpp_xor1(v2), q3 = dpp_xor1(v3);                \
        const uint32_t w0 = par ? (q2 | (v2 << 16)) : (v0 | (q0 << 16));    \
        const uint32_t w1 = par ? (q3 | (v3 << 16)) : (v1 | (q1 << 16));    \
        *reinterpret_cast<uint32_t*>(&lsn[WBASE])     = w0;                 \
        *reinterpret_cast<uint32_t*>(&lsn[WBASE + 8]) = w1; }
        WB(0, c0, wb0) WB(1, c1, wb1) WB(2, c2, wb2) WB(3, c3, wb3)

        // x_{t+1} -> als[nxt] x-region (one b128 store per thread)
        if (pf)
            *reinterpret_cast<uint4*>(&lsn[xwb]) =
                make_uint4(pk2(xv0.x, xv0.y), pk2(xv0.z, xv0.w),
                           pk2(xv1.x, xv1.y), pk2(xv1.z, xv1.w));

        __syncthreads();
        cur = nxt;
    }

    // ---- decode: out = sigmoid(h_final @ Wd + bd), 4 rows per thread ----
    {
        const int o  = tid & 63;
        const int rb = tid >> 6;             // rows rb, rb+4, rb+8, rb+12
        float s0 = bd[o], s1 = s0, s2 = s0, s3 = s0;
        const uint16_t* hb = als[cur];
        #pragma unroll 8
        for (int k = 0; k < LATENT; k += 2) {
            const float w0 = Wd[(size_t)k * OUT_DIM + o];
            const float w1 = Wd[(size_t)(k + 1) * OUT_DIM + o];
            const int bx = (k >> 3) * 128 + (k & 7);
            uint32_t p;
            p = *reinterpret_cast<const uint32_t*>(&hb[bx + (rb     ) * 8]);
            s0 += bf2f(p & 0xFFFFu) * w0 + bf2f(p >> 16) * w1;
            p = *reinterpret_cast<const uint32_t*>(&hb[bx + (rb +  4) * 8]);
            s1 += bf2f(p & 0xFFFFu) * w0 + bf2f(p >> 16) * w1;
            p = *reinterpret_cast<const uint32_t*>(&hb[bx + (rb +  8) * 8]);
            s2 += bf2f(p & 0xFFFFu) * w0 + bf2f(p >> 16) * w1;
            p = *reinterpret_cast<const uint32_t*>(&hb[bx + (rb + 12) * 8]);
            s3 += bf2f(p & 0xFFFFu) * w0 + bf2f(p >> 16) * w1;
        }
        out[(size_t)(b0 + rb     ) * OUT_DIM + o] = fast_sigmoid(s0);
        out[(size_t)(b0 + rb +  4) * OUT_DIM + o] = fast_sigmoid(s1);
        out[(size_t)(b0 + rb +  8) * OUT_DIM + o] = fast_sigmoid(s2);
        out[(size_t)(b0 + rb + 12) * OUT_DIM + o] = fast_sigmoid(s3);
    }
}

extern "C" void kernel_launch(void* const* d_in, const int* in_sizes, int n_in,
                              void* d_out, int out_size, void* d_ws, size_t ws_size,
                              hipStream_t stream) {
    const float* x  = (const float*)d_in[0];
    const float* h0 = (const float*)d_in[1];
    const float* Wi = (const float*)d_in[2];
    const float* bi = (const float*)d_in[3];
    const float* Wh = (const float*)d_in[4];
    const float* Wd = (const float*)d_in[5];
    const float* bd = (const float*)d_in[6];
    float* out = (float*)d_out;

    hipLaunchKernelGGL(rnn_mfma_w4t4, dim3(BATCH / ROWS), dim3(256), 0, stream,
                       x, h0, Wi, bi, Wh, Wd, bd, out);
}

// Round 10
// 402.791 us; speedup vs baseline: 1.3818x; 1.3818x over previous
//
#include <hip/hip_runtime.h>
#include <cmath>
#include <cstdint>

constexpr int T_STEPS = 512;
constexpr int BATCH   = 1024;
constexpr int DIM     = 128;
constexpr int LATENT  = 256;
constexpr int OUT_DIM = 64;
constexpr int ROWS    = 16;

typedef __attribute__((ext_vector_type(8))) short bf16x8;
typedef __attribute__((ext_vector_type(4))) float f32x4;
typedef __attribute__((ext_vector_type(4))) int   i32x4;

__device__ __forceinline__ uint32_t f2bf(float f) {
    uint32_t u = __builtin_bit_cast(uint32_t, f);
    return (u + 0x7FFFu + ((u >> 16) & 1u)) >> 16;
}
__device__ __forceinline__ uint32_t pk2(float a, float b) {
    return f2bf(a) | (f2bf(b) << 16);
}
__device__ __forceinline__ float fast_tanh(float v) {
    float e = __builtin_amdgcn_exp2f(v * 2.885390081777927f);   // e^{2v}
    return __builtin_fmaf(-2.0f, __builtin_amdgcn_rcpf(e + 1.0f), 1.0f);
}
__device__ __forceinline__ float fast_sigmoid(float v) {
    float e = __builtin_amdgcn_exp2f(v * -1.4426950408889634f); // e^{-v}
    return __builtin_amdgcn_rcpf(e + 1.0f);
}
__device__ __forceinline__ int q8(float v, float inv) {
    return (int)__builtin_rintf(v * inv);
}
__device__ __forceinline__ uint32_t pack4(int a, int b, int c, int d) {
    return (uint32_t)(a & 255) | ((uint32_t)(b & 255) << 8) |
           ((uint32_t)(c & 255) << 16) | ((uint32_t)(d & 255) << 24);
}
// 16B-slot swizzle: phys_slot = sl ^ (b&3) ^ ((b>>2)&3)
// -> within a 16-lane phase each (parity,bank-group) is hit exactly 2x = free.
__device__ __forceinline__ int swz(int sl, int b) {
    return (sl ^ (b & 3) ^ ((b >> 2) & 3)) & 3;
}

// grid = 64 blocks x 16 batch rows; block = 512 threads = 8 waves (2/SIMD).
// SWAPPED MFMA: C^T = W^T (A, persistent regs) x [h|x]^T (B, from LDS).
//   h-part: i8  mfma_i32_16x16x64_i8, 4 ksub (K=64) -> 4 b128 reads/wave
//   x-part: bf16 mfma_f32_16x16x32,   4 ksub (K=32) -> 4 b128 reads/wave
// -> 64 reads/CU-step (r7: 96, LDS-issue-bound). C regs = 4 consecutive
// output cols -> writeback = 1 ds_write_b32/tile, no cross-lane.
// LDS layouts (per buffer): [ksub][batch16][64B], 16B slots swizzled (swz).
// Wh quantized per-column i8 (scale colmax/127), h at fixed scale 127.
__global__ __launch_bounds__(512)
void rnn_i8h(const float* __restrict__ x,    // [512][1024][128]
             const float* __restrict__ h0,   // [1024][256]
             const float* __restrict__ Wi,   // [128][256]
             const float* __restrict__ bi,   // [256]
             const float* __restrict__ Wh,   // [256][256]
             const float* __restrict__ Wd,   // [256][64]
             const float* __restrict__ bd,   // [64]
             float* __restrict__ out)        // [1024][64]
{
    __shared__ __align__(16) uint8_t hls[2][4096];   // h^T i8,  [4][16][64B]
    __shared__ __align__(16) uint8_t xls[2][4096];   // x^T bf16,[4][16][64B]

    const int tid  = threadIdx.x;
    const int lane = tid & 63;
    const int wv   = tid >> 6;              // 0..7
    const int b0   = blockIdx.x * ROWS;
    const int b15  = lane & 15;             // batch row (B col / C col)
    const int kgrp = lane >> 4;             // 0..3
    const int tg0  = wv * 2, tg1 = wv * 2 + 1;   // global 16-col tiles
    const int wcol0 = tg0 * 16 + b15;            // A row (output col), tile0
    const int wcol1 = wcol0 + 16;

    // ---- per-column max of |Wh| (for i8 scale), lane's 64-k share + shfl ----
    float cmh0 = 0.f, cmh1 = 0.f;
    {
        const float* p0 = Wh + (size_t)(kgrp * 16) * LATENT + wcol0;
        #pragma unroll 4
        for (int i = 0; i < 64; ++i) {
            const size_t off = (size_t)((i >> 4) * 64 + (i & 15)) * LATENT;
            cmh0 = fmaxf(cmh0, fabsf(p0[off]));
            cmh1 = fmaxf(cmh1, fabsf(p0[off + 16]));
        }
        cmh0 = fmaxf(cmh0, __shfl_xor(cmh0, 16));
        cmh0 = fmaxf(cmh0, __shfl_xor(cmh0, 32));
        cmh1 = fmaxf(cmh1, __shfl_xor(cmh1, 16));
        cmh1 = fmaxf(cmh1, __shfl_xor(cmh1, 32));
    }
    const float ih0 = cmh0 > 0.f ? 127.f / cmh0 : 0.f;
    const float ih1 = cmh1 > 0.f ? 127.f / cmh1 : 0.f;

    // ---- persistent A-frags: Wh (i8) and Wi (bf16) ----
#define WHQ(J) q8(_p[(size_t)(J) * LATENT], _inv)
#define LOADWH(NAME, WC, S, INV)                                            \
    i32x4 NAME; {                                                           \
        const float* _p = Wh + (size_t)((S) * 64 + kgrp * 16) * LATENT + (WC); \
        const float _inv = (INV);                                           \
        NAME[0] = (int)pack4(WHQ(0),  WHQ(1),  WHQ(2),  WHQ(3));            \
        NAME[1] = (int)pack4(WHQ(4),  WHQ(5),  WHQ(6),  WHQ(7));            \
        NAME[2] = (int)pack4(WHQ(8),  WHQ(9),  WHQ(10), WHQ(11));           \
        NAME[3] = (int)pack4(WHQ(12), WHQ(13), WHQ(14), WHQ(15));           \
    }
    LOADWH(AH0_0, wcol0, 0, ih0) LOADWH(AH0_1, wcol0, 1, ih0)
    LOADWH(AH0_2, wcol0, 2, ih0) LOADWH(AH0_3, wcol0, 3, ih0)
    LOADWH(AH1_0, wcol1, 0, ih1) LOADWH(AH1_1, wcol1, 1, ih1)
    LOADWH(AH1_2, wcol1, 2, ih1) LOADWH(AH1_3, wcol1, 3, ih1)

#define LOADWX(NAME, WC, S)                                                 \
    bf16x8 NAME; {                                                          \
        const float* _p = Wi + (size_t)((S) * 32 + kgrp * 8) * LATENT + (WC); \
        NAME[0] = (short)f2bf(_p[0]);                                       \
        NAME[1] = (short)f2bf(_p[(size_t)1 * LATENT]);                      \
        NAME[2] = (short)f2bf(_p[(size_t)2 * LATENT]);                      \
        NAME[3] = (short)f2bf(_p[(size_t)3 * LATENT]);                      \
        NAME[4] = (short)f2bf(_p[(size_t)4 * LATENT]);                      \
        NAME[5] = (short)f2bf(_p[(size_t)5 * LATENT]);                      \
        NAME[6] = (short)f2bf(_p[(size_t)6 * LATENT]);                      \
        NAME[7] = (short)f2bf(_p[(size_t)7 * LATENT]);                      \
    }
    LOADWX(AX0_0, wcol0, 0) LOADWX(AX0_1, wcol0, 1)
    LOADWX(AX0_2, wcol0, 2) LOADWX(AX0_3, wcol0, 3)
    LOADWX(AX1_0, wcol1, 0) LOADWX(AX1_1, wcol1, 1)
    LOADWX(AX1_2, wcol1, 2) LOADWX(AX1_3, wcol1, 3)

    // dequant scales + bias per (tile, reg r): wcol = tg*16 + kgrp*4 + r
    const float dh0_0 = __shfl(cmh0, kgrp * 4 + 0) * (1.f / 16129.f);
    const float dh0_1 = __shfl(cmh0, kgrp * 4 + 1) * (1.f / 16129.f);
    const float dh0_2 = __shfl(cmh0, kgrp * 4 + 2) * (1.f / 16129.f);
    const float dh0_3 = __shfl(cmh0, kgrp * 4 + 3) * (1.f / 16129.f);
    const float dh1_0 = __shfl(cmh1, kgrp * 4 + 0) * (1.f / 16129.f);
    const float dh1_1 = __shfl(cmh1, kgrp * 4 + 1) * (1.f / 16129.f);
    const float dh1_2 = __shfl(cmh1, kgrp * 4 + 2) * (1.f / 16129.f);
    const float dh1_3 = __shfl(cmh1, kgrp * 4 + 3) * (1.f / 16129.f);
    const float cb0_0 = bi[tg0 * 16 + kgrp * 4 + 0];
    const float cb0_1 = bi[tg0 * 16 + kgrp * 4 + 1];
    const float cb0_2 = bi[tg0 * 16 + kgrp * 4 + 2];
    const float cb0_3 = bi[tg0 * 16 + kgrp * 4 + 3];
    const float cb1_0 = bi[tg1 * 16 + kgrp * 4 + 0];
    const float cb1_1 = bi[tg1 * 16 + kgrp * 4 + 1];
    const float cb1_2 = bi[tg1 * 16 + kgrp * 4 + 2];
    const float cb1_3 = bi[tg1 * 16 + kgrp * 4 + 3];

    // ---- stage h0 (i8) and x(t=0) (bf16) ----
    const int pr = tid & 15;
    const int pq = tid >> 4;                // 0..31
    const int stb = (pq >> 3) * 1024 + pr * 64 +
                    (swz((pq >> 1) & 3, pr) << 4) + (pq & 1) * 8;
    {
        const float* hp = h0 + (size_t)(b0 + pr) * LATENT + pq * 8;
        uint32_t u0 = pack4(q8(hp[0], 127.f), q8(hp[1], 127.f),
                            q8(hp[2], 127.f), q8(hp[3], 127.f));
        uint32_t u1 = pack4(q8(hp[4], 127.f), q8(hp[5], 127.f),
                            q8(hp[6], 127.f), q8(hp[7], 127.f));
        *reinterpret_cast<uint2*>(&hls[0][stb]) = make_uint2(u0, u1);
        const float* xq = x + (size_t)(b0 + pr) * DIM + pq * 4;
        float4 xv = *reinterpret_cast<const float4*>(xq);
        *reinterpret_cast<uint2*>(&xls[0][stb]) =
            make_uint2(pk2(xv.x, xv.y), pk2(xv.z, xv.w));
    }
    __syncthreads();

    const int hrd = b15 * 64 + (swz(kgrp, b15) << 4);       // B-frag base
    const int wb0 = (tg0 >> 2) * 1024 + b15 * 64 +
                    (swz(tg0 & 3, b15) << 4) + kgrp * 4;
    const int wb1 = (tg1 >> 2) * 1024 + b15 * 64 +
                    (swz(tg1 & 3, b15) << 4) + kgrp * 4;
    const float* xp = x + ((size_t)BATCH + b0 + pr) * DIM + pq * 4;  // t=1

    int cur = 0;
    for (int t = 0; t < T_STEPS; ++t) {
        const bool pf = (t + 1 < T_STEPS);
        float4 xv;
        if (pf) {
            xv = *reinterpret_cast<const float4*>(xp);
            xp += (size_t)BATCH * DIM;
        }

        const uint8_t* hb = &hls[cur][hrd];
        const uint8_t* xb = &xls[cur][hrd];
        i32x4  bh0 = *reinterpret_cast<const i32x4*>(hb);
        i32x4  bh1 = *reinterpret_cast<const i32x4*>(hb + 1024);
        i32x4  bh2 = *reinterpret_cast<const i32x4*>(hb + 2048);
        i32x4  bh3 = *reinterpret_cast<const i32x4*>(hb + 3072);
        bf16x8 bx0 = *reinterpret_cast<const bf16x8*>(xb);
        bf16x8 bx1 = *reinterpret_cast<const bf16x8*>(xb + 1024);
        bf16x8 bx2 = *reinterpret_cast<const bf16x8*>(xb + 2048);
        bf16x8 bx3 = *reinterpret_cast<const bf16x8*>(xb + 3072);

        i32x4 ch0 = {0, 0, 0, 0}, ch1 = {0, 0, 0, 0};
        f32x4 cx0 = {cb0_0, cb0_1, cb0_2, cb0_3};
        f32x4 cx1 = {cb1_0, cb1_1, cb1_2, cb1_3};

        ch0 = __builtin_amdgcn_mfma_i32_16x16x64_i8(AH0_0, bh0, ch0, 0, 0, 0);
        ch1 = __builtin_amdgcn_mfma_i32_16x16x64_i8(AH1_0, bh0, ch1, 0, 0, 0);
        cx0 = __builtin_amdgcn_mfma_f32_16x16x32_bf16(AX0_0, bx0, cx0, 0, 0, 0);
        cx1 = __builtin_amdgcn_mfma_f32_16x16x32_bf16(AX1_0, bx0, cx1, 0, 0, 0);
        ch0 = __builtin_amdgcn_mfma_i32_16x16x64_i8(AH0_1, bh1, ch0, 0, 0, 0);
        ch1 = __builtin_amdgcn_mfma_i32_16x16x64_i8(AH1_1, bh1, ch1, 0, 0, 0);
        cx0 = __builtin_amdgcn_mfma_f32_16x16x32_bf16(AX0_1, bx1, cx0, 0, 0, 0);
        cx1 = __builtin_amdgcn_mfma_f32_16x16x32_bf16(AX1_1, bx1, cx1, 0, 0, 0);
        ch0 = __builtin_amdgcn_mfma_i32_16x16x64_i8(AH0_2, bh2, ch0, 0, 0, 0);
        ch1 = __builtin_amdgcn_mfma_i32_16x16x64_i8(AH1_2, bh2, ch1, 0, 0, 0);
        cx0 = __builtin_amdgcn_mfma_f32_16x16x32_bf16(AX0_2, bx2, cx0, 0, 0, 0);
        cx1 = __builtin_amdgcn_mfma_f32_16x16x32_bf16(AX1_2, bx2, cx1, 0, 0, 0);
        ch0 = __builtin_amdgcn_mfma_i32_16x16x64_i8(AH0_3, bh3, ch0, 0, 0, 0);
        ch1 = __builtin_amdgcn_mfma_i32_16x16x64_i8(AH1_3, bh3, ch1, 0, 0, 0);
        cx0 = __builtin_amdgcn_mfma_f32_16x16x32_bf16(AX0_3, bx3, cx0, 0, 0, 0);
        cx1 = __builtin_amdgcn_mfma_f32_16x16x32_bf16(AX1_3, bx3, cx1, 0, 0, 0);

        const int nxt = cur ^ 1;
        {   // tile0: combine (bias in cx init) -> tanh -> i8 -> one b32 write
            float v0 = fast_tanh(__builtin_fmaf((float)ch0[0], dh0_0, cx0[0]));
            float v1 = fast_tanh(__builtin_fmaf((float)ch0[1], dh0_1, cx0[1]));
            float v2 = fast_tanh(__builtin_fmaf((float)ch0[2], dh0_2, cx0[2]));
            float v3 = fast_tanh(__builtin_fmaf((float)ch0[3], dh0_3, cx0[3]));
            *reinterpret_cast<uint32_t*>(&hls[nxt][wb0]) =
                pack4(q8(v0, 127.f), q8(v1, 127.f), q8(v2, 127.f), q8(v3, 127.f));
        }
        {   // tile1
            float v0 = fast_tanh(__builtin_fmaf((float)ch1[0], dh1_0, cx1[0]));
            float v1 = fast_tanh(__builtin_fmaf((float)ch1[1], dh1_1, cx1[1]));
            float v2 = fast_tanh(__builtin_fmaf((float)ch1[2], dh1_2, cx1[2]));
            float v3 = fast_tanh(__builtin_fmaf((float)ch1[3], dh1_3, cx1[3]));
            *reinterpret_cast<uint32_t*>(&hls[nxt][wb1]) =
                pack4(q8(v0, 127.f), q8(v1, 127.f), q8(v2, 127.f), q8(v3, 127.f));
        }
        if (pf)
            *reinterpret_cast<uint2*>(&xls[nxt][stb]) =
                make_uint2(pk2(xv.x, xv.y), pk2(xv.z, xv.w));

        __syncthreads();
        cur = nxt;
    }

    // ---- decode: out = sigmoid(h/127 @ Wd + bd), 2 rows per thread ----
    {
        const int o  = tid & 63;
        const int rb = tid >> 6;            // rows rb, rb+8
        float s0 = 0.f, s1 = 0.f;
        #pragma unroll 4
        for (int k = 0; k < LATENT; k += 4) {
            const int sl   = (k >> 4) & 3;
            const int base = (k >> 6) * 1024 + (k & 15);
            const uint32_t pA = *reinterpret_cast<const uint32_t*>(
                &hls[cur][base + rb * 64 + (swz(sl, rb) << 4)]);
            const uint32_t pB = *reinterpret_cast<const uint32_t*>(
                &hls[cur][base + (rb + 8) * 64 + (swz(sl, rb + 8) << 4)]);
            const float w0 = Wd[(size_t)(k + 0) * OUT_DIM + o];
            const float w1 = Wd[(size_t)(k + 1) * OUT_DIM + o];
            const float w2 = Wd[(size_t)(k + 2) * OUT_DIM + o];
            const float w3 = Wd[(size_t)(k + 3) * OUT_DIM + o];
            s0 += (float)(int8_t)(pA) * w0 + (float)(int8_t)(pA >> 8) * w1
                + (float)(int8_t)(pA >> 16) * w2 + (float)(int8_t)(pA >> 24) * w3;
            s1 += (float)(int8_t)(pB) * w0 + (float)(int8_t)(pB >> 8) * w1
                + (float)(int8_t)(pB >> 16) * w2 + (float)(int8_t)(pB >> 24) * w3;
        }
        out[(size_t)(b0 + rb) * OUT_DIM + o] =
            fast_sigmoid(bd[o] + s0 * (1.f / 127.f));
        out[(size_t)(b0 + rb + 8) * OUT_DIM + o] =
            fast_sigmoid(bd[o] + s1 * (1.f / 127.f));
    }
}

extern "C" void kernel_launch(void* const* d_in, const int* in_sizes, int n_in,
                              void* d_out, int out_size, void* d_ws, size_t ws_size,
                              hipStream_t stream) {
    const float* x  = (const float*)d_in[0];
    const float* h0 = (const float*)d_in[1];
    const float* Wi = (const float*)d_in[2];
    const float* bi = (const float*)d_in[3];
    const float* Wh = (const float*)d_in[4];
    const float* Wd = (const float*)d_in[5];
    const float* bd = (const float*)d_in[6];
    float* out = (float*)d_out;

    hipLaunchKernelGGL(rnn_i8h, dim3(BATCH / ROWS), dim3(512), 0, stream,
                       x, h0, Wi, bi, Wh, Wd, bd, out);
}